// Round 2
// baseline (274.531 us; speedup 1.0000x reference)
//
#include <hip/hip_runtime.h>
#include <hip/hip_bf16.h>

#define DEV_INLINE __device__ __forceinline__

constexpr int E   = 16;
constexpr int F   = 19;
constexpr int H   = 128;
constexpr int D   = 64;
constexpr int KX  = 48;     // 3*E
constexpr int BLK = 512;    // threads per block (8 waves); block handles BLK rows
constexpr float EPSV = 1e-5f;

// d_ws float layout:
//   [0      , 6144)  WshT[j][k]  (W_sh transposed, row j contiguous over k=0..47)
//   [6144   , 6272)  scale[j] = bn_gamma*rsqrt(bn_var+eps)
//   [6272   , 6400)  shift[j] = (b_sh - bn_mean)*scale + bn_beta
__global__ void prep_kernel(const float* __restrict__ W_sh, const float* __restrict__ b_sh,
                            const float* __restrict__ bn_g, const float* __restrict__ bn_b,
                            const float* __restrict__ bn_m, const float* __restrict__ bn_v,
                            float* __restrict__ ws)
{
    int j = threadIdx.x;
    if (j < H) {
        float sc = bn_g[j] * rsqrtf(bn_v[j] + EPSV);
        ws[6144 + j] = sc;
        ws[6272 + j] = (b_sh[j] - bn_m[j]) * sc + bn_b[j];
        for (int k = 0; k < KX; ++k)
            ws[j * KX + k] = W_sh[k * H + j];
    }
}

// Full per-row tail: shared_fc (via folded scale/shift) -> expert matvec -> LN -> relu
// -> head dot -> sigmoid. eb/be/lg/lb are the sport-selected expert params; in the
// wave-uniform call site they are scalar (SGPR) pointers -> s_load broadcasts.
DEV_INLINE float row_tail(const float* x,
                          const float* __restrict__ wsT,
                          const float* __restrict__ wscale,
                          const float* __restrict__ wshift,
                          const float* __restrict__ eb,
                          const float* __restrict__ be,
                          const float* __restrict__ lg,
                          const float* __restrict__ lb,
                          const float* __restrict__ wout,
                          float bout)
{
    float h[D];
#pragma unroll
    for (int d = 0; d < D; ++d) h[d] = be[d];

    for (int j = 0; j < H; ++j) {
        const float* wr = wsT + j * KX;
        float a0 = 0.f, a1 = 0.f, a2 = 0.f, a3 = 0.f;
#pragma unroll
        for (int k = 0; k < KX; k += 4) {
            a0 = fmaf(x[k+0], wr[k+0], a0);
            a1 = fmaf(x[k+1], wr[k+1], a1);
            a2 = fmaf(x[k+2], wr[k+2], a2);
            a3 = fmaf(x[k+3], wr[k+3], a3);
        }
        float s = (a0 + a1) + (a2 + a3);
        s = fmaf(s, wscale[j], wshift[j]);  // BN folded (incl. b_sh)
        s = fmaxf(s, 0.f);                  // ReLU
        const float* er = eb + j * D;
#pragma unroll
        for (int d = 0; d < D; ++d) h[d] = fmaf(s, er[d], h[d]);
    }

    // LayerNorm over D (biased var), gamma/beta, ReLU, head dot, sigmoid
    float s0=0.f,s1=0.f,s2=0.f,s3=0.f;
#pragma unroll
    for (int d = 0; d < D; d += 4) { s0+=h[d]; s1+=h[d+1]; s2+=h[d+2]; s3+=h[d+3]; }
    float mean = ((s0+s1)+(s2+s3)) * (1.f/(float)D);

    float v0=0.f,v1=0.f,v2=0.f,v3=0.f;
#pragma unroll
    for (int d = 0; d < D; d += 4) {
        float c0=h[d+0]-mean, c1=h[d+1]-mean, c2=h[d+2]-mean, c3=h[d+3]-mean;
        v0=fmaf(c0,c0,v0); v1=fmaf(c1,c1,v1); v2=fmaf(c2,c2,v2); v3=fmaf(c3,c3,v3);
    }
    float inv = rsqrtf(((v0+v1)+(v2+v3)) * (1.f/(float)D) + EPSV);

    float z0=0.f,z1=0.f,z2=0.f,z3=0.f;
#pragma unroll
    for (int d = 0; d < D; d += 4) {
        float h0 = fmaxf(fmaf((h[d+0]-mean)*inv, lg[d+0], lb[d+0]), 0.f);
        float h1 = fmaxf(fmaf((h[d+1]-mean)*inv, lg[d+1], lb[d+1]), 0.f);
        float h2 = fmaxf(fmaf((h[d+2]-mean)*inv, lg[d+2], lb[d+2]), 0.f);
        float h3 = fmaxf(fmaf((h[d+3]-mean)*inv, lg[d+3], lb[d+3]), 0.f);
        z0 = fmaf(h0, wout[d+0], z0);
        z1 = fmaf(h1, wout[d+1], z1);
        z2 = fmaf(h2, wout[d+2], z2);
        z3 = fmaf(h3, wout[d+3], z3);
    }
    float z = ((z0+z1)+(z2+z3)) + bout;
    return 1.f / (1.f + __expf(-z));
}

__global__ __launch_bounds__(BLK) void ncf_main(
    const int*   __restrict__ home,  const int* __restrict__ away,
    const float* __restrict__ gfeat, const int* __restrict__ sport,
    const float* __restrict__ emb_h, const float* __restrict__ emb_a,
    const float* __restrict__ W_gf,  const float* __restrict__ b_gf,
    const float* __restrict__ Wexp,  const float* __restrict__ bexp,
    const float* __restrict__ ln_g,  const float* __restrict__ ln_b,
    const float* __restrict__ wout,  const float* __restrict__ bo,
    const float* __restrict__ ws,
    float* __restrict__ out)
{
    __shared__ int cnt[3], basep[3], cur[3];
    __shared__ unsigned short perm[BLK];

    const int tid = threadIdx.x;
    const int r0  = blockIdx.x * BLK;

    // ---- local 3-bucket sport compaction so waves are (mostly) sport-pure ----
    if (tid < 3) { cnt[tid] = 0; cur[tid] = 0; }
    __syncthreads();
    int spRaw = sport[r0 + tid];
    atomicAdd(&cnt[spRaw], 1);
    __syncthreads();
    if (tid == 0) { basep[0] = 0; basep[1] = cnt[0]; basep[2] = cnt[0] + cnt[1]; }
    __syncthreads();
    int pos = basep[spRaw] + atomicAdd(&cur[spRaw], 1);
    perm[pos] = (unsigned short)tid;
    __syncthreads();

    const int r  = r0 + (int)perm[tid];
    const int sp = sport[r];

    // ---- build x = [emb_home | emb_away | relu(gf @ W_gf + b_gf)] ----
    float x[KX];
    {
        const int ht = home[r], at = away[r];
        const float4* ph = reinterpret_cast<const float4*>(emb_h + (size_t)ht * E);
        const float4* pa = reinterpret_cast<const float4*>(emb_a + (size_t)at * E);
#pragma unroll
        for (int q = 0; q < 4; ++q) {
            float4 v = ph[q];
            x[q*4+0]=v.x; x[q*4+1]=v.y; x[q*4+2]=v.z; x[q*4+3]=v.w;
        }
#pragma unroll
        for (int q = 0; q < 4; ++q) {
            float4 v = pa[q];
            x[16+q*4+0]=v.x; x[16+q*4+1]=v.y; x[16+q*4+2]=v.z; x[16+q*4+3]=v.w;
        }
        float gl[F];
        const float* gr = gfeat + (size_t)r * F;
#pragma unroll
        for (int f = 0; f < F; ++f) gl[f] = gr[f];
        float acc[E];
#pragma unroll
        for (int e = 0; e < E; ++e) acc[e] = b_gf[e];
#pragma unroll 2
        for (int f = 0; f < F; ++f) {
            const float* wf = W_gf + f * E;
#pragma unroll
            for (int e = 0; e < E; ++e) acc[e] = fmaf(gl[f], wf[e], acc[e]);
        }
#pragma unroll
        for (int e = 0; e < E; ++e) x[32 + e] = fmaxf(acc[e], 0.f);
    }

    const float* wsT    = ws;
    const float* wscale = ws + 6144;
    const float* wshift = ws + 6272;
    const float  bout   = bo[0];

    // ---- sport-pure waves: scalarize expert pointers -> SMEM broadcast loads ----
    int sp_first = __builtin_amdgcn_readfirstlane(sp);
    float y;
    if (__all(sp == sp_first)) {
        const int spu = sp_first;
        y = row_tail(x, wsT, wscale, wshift,
                     Wexp + (size_t)spu * H * D, bexp + spu * D,
                     ln_g + spu * D, ln_b + spu * D, wout, bout);
    } else {
        y = row_tail(x, wsT, wscale, wshift,
                     Wexp + (size_t)sp * H * D, bexp + sp * D,
                     ln_g + sp * D, ln_b + sp * D, wout, bout);
    }

    out[r] = y;
}

extern "C" void kernel_launch(void* const* d_in, const int* in_sizes, int n_in,
                              void* d_out, int out_size, void* d_ws, size_t ws_size,
                              hipStream_t stream) {
    const int*   home  = (const int*)  d_in[0];
    const int*   away  = (const int*)  d_in[1];
    const float* gf    = (const float*)d_in[2];
    const int*   sport = (const int*)  d_in[3];
    const float* emb_h = (const float*)d_in[4];
    const float* emb_a = (const float*)d_in[5];
    const float* W_gf  = (const float*)d_in[6];
    const float* b_gf  = (const float*)d_in[7];
    const float* W_sh  = (const float*)d_in[8];
    const float* b_sh  = (const float*)d_in[9];
    const float* bn_g  = (const float*)d_in[10];
    const float* bn_b  = (const float*)d_in[11];
    const float* bn_m  = (const float*)d_in[12];
    const float* bn_v  = (const float*)d_in[13];
    const float* Wexp  = (const float*)d_in[14];
    const float* bexp  = (const float*)d_in[15];
    const float* ln_g  = (const float*)d_in[16];
    const float* ln_b  = (const float*)d_in[17];
    const float* wout  = (const float*)d_in[18];
    const float* bo    = (const float*)d_in[19];

    float* ws  = (float*)d_ws;        // needs 25600 B
    float* out = (float*)d_out;       // fp32 output, [B,1]

    const int B = in_sizes[0];        // 262144, divisible by BLK

    prep_kernel<<<1, 128, 0, stream>>>(W_sh, b_sh, bn_g, bn_b, bn_m, bn_v, ws);
    ncf_main<<<B / BLK, BLK, 0, stream>>>(home, away, gf, sport, emb_h, emb_a,
                                          W_gf, b_gf, Wexp, bexp, ln_g, ln_b,
                                          wout, bo, ws, out);
}

// Round 4
// 174.592 us; speedup vs baseline: 1.5724x; 1.5724x over previous
//
#include <hip/hip_runtime.h>
#include <hip/hip_bf16.h>
#include <stdint.h>

#define DEV_INLINE __device__ __forceinline__

typedef short          short8 __attribute__((ext_vector_type(8)));   // MFMA A/B operand (8 bf16)
typedef unsigned short u16x8  __attribute__((ext_vector_type(8)));
typedef unsigned int   u32x4  __attribute__((ext_vector_type(4)));
typedef float          f32x4  __attribute__((ext_vector_type(4)));

constexpr int   MB_  = 128;   // rows per block
constexpr int   BLKT = 256;   // threads (4 waves)
constexpr float EPSV = 1e-5f;

// Swizzled LDS index helpers (16B-group XOR swizzle -> <=2-way bank conflicts on
// all MFMA fragment reads). Element granularity: bf16; groups of 8 bf16 = 16B.
#define XIDX(r,c)  (((r)<<6) + ((((c)>>3) ^ ((r)&7))<<3)  + ((c)&7))   // X  [128 r][64 c]
#define WSIDX(c,k) (((c)<<6) + ((((k)>>3) ^ ((c)&7))<<3)  + ((k)&7))   // Wsh[128 c][64 k] (col-major)
#define SIDX(r,j)  (((r)<<7) + ((((j)>>3) ^ ((r)&15))<<3) + ((j)&7))   // S  [128 r][128 j]
#define WEIDX(c,k) (((c)<<7) + ((((k)>>3) ^ ((c)&15))<<3) + ((k)&7))   // Wexp buf [64 c][128 k]

static DEV_INLINE unsigned short f2bf(float f) {
    return __builtin_bit_cast(unsigned short, __float2bfloat16(f));   // RNE
}

__global__ __launch_bounds__(BLKT, 2) void fused_kernel(
    const int*   __restrict__ home,  const int* __restrict__ away,
    const float* __restrict__ gfeat, const int* __restrict__ sport,
    const float* __restrict__ emb_h, const float* __restrict__ emb_a,
    const float* __restrict__ W_gf,  const float* __restrict__ b_gf,
    const float* __restrict__ W_sh,  const float* __restrict__ b_sh,
    const float* __restrict__ bn_g,  const float* __restrict__ bn_b,
    const float* __restrict__ bn_m,  const float* __restrict__ bn_v,
    const float* __restrict__ Wexp,  const float* __restrict__ bexp,
    const float* __restrict__ ln_g,  const float* __restrict__ ln_b,
    const float* __restrict__ wout,  const float* __restrict__ bo,
    float* __restrict__ out)
{
    __shared__ __align__(16) unsigned char smem[65536];   // exactly 64 KiB -> 2 blocks/CU
    unsigned short* Xl = (unsigned short*)(smem);          // [128][64] swz X; later Wexp buf0 (16KB)
    unsigned short* Wl = (unsigned short*)(smem + 16384);  // [128][64] swz Wsh col-major; later buf1
    unsigned short* Sl = (unsigned short*)(smem + 32768);  // [128][128] swz S (bf16, post BN+ReLU)

    const int tid  = threadIdx.x;
    const int r0   = blockIdx.x * MB_;
    const int lane = tid & 63;
    const int w    = tid >> 6;         // wave 0..3
    const int llo  = lane & 15;
    const int lhi  = lane >> 4;

    // ================= phase 0: build X (threads 0-127) | stage Wsh (threads 128-255) =======
    if (tid < 128) {
        const int r = r0 + tid;
        float x[48];
        {
            const int ht = home[r], at = away[r];
            const float4* ph = (const float4*)(emb_h + (size_t)ht * 16);
            const float4* pa = (const float4*)(emb_a + (size_t)at * 16);
#pragma unroll
            for (int q = 0; q < 4; ++q) { float4 v = ph[q]; x[q*4]=v.x; x[q*4+1]=v.y; x[q*4+2]=v.z; x[q*4+3]=v.w; }
#pragma unroll
            for (int q = 0; q < 4; ++q) { float4 v = pa[q]; x[16+q*4]=v.x; x[16+q*4+1]=v.y; x[16+q*4+2]=v.z; x[16+q*4+3]=v.w; }
            float gl[19];
            const float* gr = gfeat + (size_t)r * 19;
#pragma unroll
            for (int f = 0; f < 19; ++f) gl[f] = gr[f];
            float ag[16];
#pragma unroll
            for (int e = 0; e < 16; ++e) ag[e] = b_gf[e];
#pragma unroll 2
            for (int f = 0; f < 19; ++f) {
                const float* wf = W_gf + f * 16;
#pragma unroll
                for (int e = 0; e < 16; ++e) ag[e] = fmaf(gl[f], wf[e], ag[e]);
            }
#pragma unroll
            for (int e = 0; e < 16; ++e) x[32+e] = fmaxf(ag[e], 0.f);
        }
#pragma unroll
        for (int g = 0; g < 8; ++g) {                 // pack 8 bf16 -> one b128 store
            u16x8 v;
#pragma unroll
            for (int j = 0; j < 8; ++j) {
                const int c = g*8 + j;
                v[j] = (c < 48) ? f2bf(x[c]) : (unsigned short)0;
            }
            *(u32x4*)&Xl[XIDX(tid, g*8)] = __builtin_bit_cast(u32x4, v);
        }
    } else {
        const int c2 = tid - 128;                     // Wsh column (output feature) 0..127
        float wk[48];
#pragma unroll 8
        for (int k = 0; k < 48; ++k) wk[k] = W_sh[k * 128 + c2];   // coalesced per k
#pragma unroll
        for (int g = 0; g < 8; ++g) {
            u16x8 v;
#pragma unroll
            for (int j = 0; j < 8; ++j) {
                const int k = g*8 + j;
                v[j] = (k < 48) ? f2bf(wk[k]) : (unsigned short)0;
            }
            *(u32x4*)&Wl[WSIDX(c2, g*8)] = __builtin_bit_cast(u32x4, v);
        }
    }
    __syncthreads();

    // ================= phase 1: S[128,128] = X @ Wsh  (each wave: 2 M-tiles x 8 N-tiles) ====
    f32x4 acc[2][8];
#pragma unroll
    for (int mt = 0; mt < 2; ++mt)
#pragma unroll
        for (int nt = 0; nt < 8; ++nt) acc[mt][nt] = (f32x4){0.f, 0.f, 0.f, 0.f};

#pragma unroll
    for (int kk = 0; kk < 2; ++kk) {
        short8 a0 = *(const short8*)&Xl[XIDX((w*2+0)*16 + llo, kk*32 + lhi*8)];
        short8 a1 = *(const short8*)&Xl[XIDX((w*2+1)*16 + llo, kk*32 + lhi*8)];
#pragma unroll
        for (int nt = 0; nt < 8; ++nt) {
            short8 b = *(const short8*)&Wl[WSIDX(nt*16 + llo, kk*32 + lhi*8)];
            acc[0][nt] = __builtin_amdgcn_mfma_f32_16x16x32_bf16(a0, b, acc[0][nt], 0, 0, 0);
            acc[1][nt] = __builtin_amdgcn_mfma_f32_16x16x32_bf16(a1, b, acc[1][nt], 0, 0, 0);
        }
    }

    // T14 split: issue expert-0 weight loads now; HBM/L2 latency hides under S epilogue.
    const int cs  = tid & 63;            // expert output column d
    const int kg0 = (tid >> 6) * 4;      // first of this thread's 4 k-groups (8 k each)
    float stg[4][8];
#pragma unroll
    for (int i = 0; i < 4; ++i)
#pragma unroll
        for (int j = 0; j < 8; ++j)
            stg[i][j] = Wexp[((kg0 + i)*8 + j) * 64 + cs];          // coalesced per (i,j)

    // ---- S epilogue: BN fold (scale/shift recomputed per-lane) + ReLU -> Sl (bf16) ----
#pragma unroll
    for (int nt = 0; nt < 8; ++nt) {
        const int col = nt*16 + llo;
        const float sc = bn_g[col] * rsqrtf(bn_v[col] + EPSV);
        const float sh = (b_sh[col] - bn_m[col]) * sc + bn_b[col];
#pragma unroll
        for (int e = 0; e < 4; ++e) {
            const int ro = (w*2)*16 + lhi*4 + e;
            Sl[SIDX(ro,      col)] = f2bf(fmaxf(fmaf(acc[0][nt][e], sc, sh), 0.f));
            Sl[SIDX(ro + 16, col)] = f2bf(fmaxf(fmaf(acc[1][nt][e], sc, sh), 0.f));
        }
    }
    __syncthreads();

    // write stage-0 expert weights into buf0 (aliases dead X region)
    {
        unsigned short* B0 = (unsigned short*)smem;
#pragma unroll
        for (int i = 0; i < 4; ++i) {
            u16x8 v;
#pragma unroll
            for (int j = 0; j < 8; ++j) v[j] = f2bf(stg[i][j]);
            *(u32x4*)&B0[WEIDX(cs, (kg0 + i)*8)] = __builtin_bit_cast(u32x4, v);
        }
    }
    __syncthreads();

    // A fragments for phase 2 + per-row sport preload (latency overlap)
    short8 af[2][4];
#pragma unroll
    for (int mt = 0; mt < 2; ++mt)
#pragma unroll
        for (int kk = 0; kk < 4; ++kk)
            af[mt][kk] = *(const short8*)&Sl[SIDX((w*2+mt)*16 + llo, kk*32 + lhi*8)];

    int spv[2][4];
#pragma unroll
    for (int mt = 0; mt < 2; ++mt)
#pragma unroll
        for (int e = 0; e < 4; ++e)
            spv[mt][e] = sport[r0 + (w*2+mt)*16 + lhi*4 + e];

    // ================= phase 2: H_s = S @ Wexp[s] for s=0..2 (double-buffered) =============
    f32x4 acce[2][12];
#pragma unroll
    for (int mt = 0; mt < 2; ++mt)
#pragma unroll
        for (int t = 0; t < 12; ++t) acce[mt][t] = (f32x4){0.f, 0.f, 0.f, 0.f};

#pragma unroll
    for (int s = 0; s < 3; ++s) {
        if (s < 2) {                                   // issue next sport's loads early
#pragma unroll
            for (int i = 0; i < 4; ++i)
#pragma unroll
                for (int j = 0; j < 8; ++j)
                    stg[i][j] = Wexp[(s+1)*8192 + ((kg0 + i)*8 + j)*64 + cs];
        }
        const unsigned short* Bc = (const unsigned short*)smem + (s & 1) * 8192;
#pragma unroll
        for (int kk = 0; kk < 4; ++kk) {
#pragma unroll
            for (int nt = 0; nt < 4; ++nt) {
                short8 b = *(const short8*)&Bc[WEIDX(nt*16 + llo, kk*32 + lhi*8)];
                acce[0][s*4+nt] = __builtin_amdgcn_mfma_f32_16x16x32_bf16(af[0][kk], b, acce[0][s*4+nt], 0, 0, 0);
                acce[1][s*4+nt] = __builtin_amdgcn_mfma_f32_16x16x32_bf16(af[1][kk], b, acce[1][s*4+nt], 0, 0, 0);
            }
        }
        if (s < 2) {                                   // write-late into the other buffer
            unsigned short* Bn = (unsigned short*)smem + ((s+1) & 1) * 8192;
#pragma unroll
            for (int i = 0; i < 4; ++i) {
                u16x8 v;
#pragma unroll
                for (int j = 0; j < 8; ++j) v[j] = f2bf(stg[i][j]);
                *(u32x4*)&Bn[WEIDX(cs, (kg0 + i)*8)] = __builtin_bit_cast(u32x4, v);
            }
            __syncthreads();
        }
    }

    // ================= tail: per-row select + LayerNorm + ReLU + head + sigmoid ============
    float wo[4], lgp[3][4], lbp[3][4], bep[3][4];
#pragma unroll
    for (int nt = 0; nt < 4; ++nt) wo[nt] = wout[nt*16 + llo];
#pragma unroll
    for (int s = 0; s < 3; ++s)
#pragma unroll
        for (int nt = 0; nt < 4; ++nt) {
            lgp[s][nt] = ln_g[s*64 + nt*16 + llo];
            lbp[s][nt] = ln_b[s*64 + nt*16 + llo];
            bep[s][nt] = bexp[s*64 + nt*16 + llo];
        }
    const float bo0 = bo[0];

#pragma unroll
    for (int mt = 0; mt < 2; ++mt) {
#pragma unroll
        for (int e = 0; e < 4; ++e) {
            const int rl = (w*2+mt)*16 + lhi*4 + e;    // row within block
            const int sp = spv[mt][e];
            float h[4];
#pragma unroll
            for (int nt = 0; nt < 4; ++nt) {
                float v  = (sp == 0) ? acce[mt][nt][e] : (sp == 1 ? acce[mt][4+nt][e] : acce[mt][8+nt][e]);
                float bb = (sp == 0) ? bep[0][nt]      : (sp == 1 ? bep[1][nt]        : bep[2][nt]);
                h[nt] = v + bb;
            }
            // mean over 64 cols: 4 per-lane partials + 16-lane butterfly
            float m = (h[0] + h[1]) + (h[2] + h[3]);
            m += __shfl_xor(m, 1); m += __shfl_xor(m, 2); m += __shfl_xor(m, 4); m += __shfl_xor(m, 8);
            m *= (1.0f / 64.0f);
            float vv = 0.f;
#pragma unroll
            for (int nt = 0; nt < 4; ++nt) { float c = h[nt] - m; vv = fmaf(c, c, vv); }
            vv += __shfl_xor(vv, 1); vv += __shfl_xor(vv, 2); vv += __shfl_xor(vv, 4); vv += __shfl_xor(vv, 8);
            const float inv = rsqrtf(vv * (1.0f / 64.0f) + EPSV);
            float z = 0.f;
#pragma unroll
            for (int nt = 0; nt < 4; ++nt) {
                float g_ = (sp == 0) ? lgp[0][nt] : (sp == 1 ? lgp[1][nt] : lgp[2][nt]);
                float b_ = (sp == 0) ? lbp[0][nt] : (sp == 1 ? lbp[1][nt] : lbp[2][nt]);
                float hn = fmaf((h[nt] - m) * inv, g_, b_);
                hn = fmaxf(hn, 0.f);
                z  = fmaf(hn, wo[nt], z);
            }
            z += __shfl_xor(z, 1); z += __shfl_xor(z, 2); z += __shfl_xor(z, 4); z += __shfl_xor(z, 8);
            if (llo == 0) out[r0 + rl] = 1.0f / (1.0f + __expf(-(z + bo0)));
        }
    }
}

extern "C" void kernel_launch(void* const* d_in, const int* in_sizes, int n_in,
                              void* d_out, int out_size, void* d_ws, size_t ws_size,
                              hipStream_t stream) {
    const int*   home  = (const int*)  d_in[0];
    const int*   away  = (const int*)  d_in[1];
    const float* gf    = (const float*)d_in[2];
    const int*   sport = (const int*)  d_in[3];
    const float* emb_h = (const float*)d_in[4];
    const float* emb_a = (const float*)d_in[5];
    const float* W_gf  = (const float*)d_in[6];
    const float* b_gf  = (const float*)d_in[7];
    const float* W_sh  = (const float*)d_in[8];
    const float* b_sh  = (const float*)d_in[9];
    const float* bn_g  = (const float*)d_in[10];
    const float* bn_b  = (const float*)d_in[11];
    const float* bn_m  = (const float*)d_in[12];
    const float* bn_v  = (const float*)d_in[13];
    const float* Wexp  = (const float*)d_in[14];
    const float* bexp  = (const float*)d_in[15];
    const float* ln_g  = (const float*)d_in[16];
    const float* ln_b  = (const float*)d_in[17];
    const float* wout  = (const float*)d_in[18];
    const float* bo    = (const float*)d_in[19];
    float* out = (float*)d_out;

    const int B = in_sizes[0];                 // 262144 = 2048 * 128
    fused_kernel<<<B / MB_, BLKT, 0, stream>>>(home, away, gf, sport, emb_h, emb_a,
                                               W_gf, b_gf, W_sh, b_sh,
                                               bn_g, bn_b, bn_m, bn_v,
                                               Wexp, bexp, ln_g, ln_b, wout, bo, out);
}